// Round 1
// baseline (2968.045 us; speedup 1.0000x reference)
//
#include <hip/hip_runtime.h>

#define NB    8
#define NCIN  256
#define NH    128
#define NW    128
#define NHW   16384      // NH*NW
#define NQKV  192        // 3*T
#define NCOUT 256

// ---------------------------------------------------------------------------
// K1: qkv[b][m][n] = sum_k Wq[m][k] * x[b][k][n]   (1x1 conv as panel GEMM)
// Rewritten as a classic double-buffered LDS-tiled fp32 GEMM.
//   BM=64, BN=256, BK=16, 256 threads, 8m x 8n register tile per thread.
// Old version fetched 1 KB of block-uniform weights per k-iter through the
// scalar path (112 SGPRs -> chunked s_load + lgkmcnt serialization,
// VALUBusy 23%). Now both operands stream through LDS; per k-step:
// 4x ds_read_b128 (2 broadcast for A, 2 conflict-light for B) feed 64 FMAs.
// ---------------------------------------------------------------------------
#define K1_BK  16
#define K1_LDA 68       // 64 + 4 pad (kills staging ds_write conflicts)
#define K1_LDB 260      // 256 + 4 pad

__global__ __launch_bounds__(256, 3) void k1_qkv(
    const float* __restrict__ x, const float* __restrict__ Wq,
    float* __restrict__ qkv)
{
  __shared__ float As[2][K1_BK][K1_LDA];
  __shared__ float Bs[2][K1_BK][K1_LDB];

  const int tid = threadIdx.x;
  const int b   = blockIdx.x >> 6;          // 64 n-tiles per batch
  const int n0  = (blockIdx.x & 63) << 8;   // *256
  const int m0  = blockIdx.y << 6;          // *64

  // staging assignment
  const int am = tid >> 2;                  // 0..63  m within tile
  const int ak = (tid & 3) << 2;            // 0,4,8,12 k within tile
  const int bk = tid >> 4;                  // 0..15 k within tile
  const int bn = (tid & 15) << 2;           // 0..60 n base (stride 64)

  const float* aP = Wq + ((size_t)(m0 + am) << 8) + ak;
  const float* bP = x + (size_t)b * NCIN * NHW + (size_t)bk * NHW + n0 + bn;

  // compute-thread mapping: 32 n-groups x 8 m-groups
  const int tx = tid & 31;
  const int ty = tid >> 5;

  float4 ra, rb0, rb1, rb2, rb3;
  ra  = *(const float4*)aP;
  rb0 = *(const float4*)(bP);
  rb1 = *(const float4*)(bP + 64);
  rb2 = *(const float4*)(bP + 128);
  rb3 = *(const float4*)(bP + 192);

  As[0][ak + 0][am] = ra.x;
  As[0][ak + 1][am] = ra.y;
  As[0][ak + 2][am] = ra.z;
  As[0][ak + 3][am] = ra.w;
  *(float4*)&Bs[0][bk][bn]       = rb0;
  *(float4*)&Bs[0][bk][bn + 64]  = rb1;
  *(float4*)&Bs[0][bk][bn + 128] = rb2;
  *(float4*)&Bs[0][bk][bn + 192] = rb3;
  __syncthreads();

  float acc[8][8];
#pragma unroll
  for (int i = 0; i < 8; i++)
#pragma unroll
    for (int j = 0; j < 8; j++) acc[i][j] = 0.f;

  int cur = 0;
  for (int t = 0; t < 16; ++t) {
    if (t < 15) {
      const size_t k0 = (size_t)(t + 1) * K1_BK;
      ra = *(const float4*)(aP + k0);
      const float* bq = bP + k0 * NHW;
      rb0 = *(const float4*)(bq);
      rb1 = *(const float4*)(bq + 64);
      rb2 = *(const float4*)(bq + 128);
      rb3 = *(const float4*)(bq + 192);
    }
#pragma unroll
    for (int kk = 0; kk < K1_BK; ++kk) {
      float a[8], bb[8];
      *(float4*)&a[0]  = *(const float4*)&As[cur][kk][ty * 4];
      *(float4*)&a[4]  = *(const float4*)&As[cur][kk][32 + ty * 4];
      *(float4*)&bb[0] = *(const float4*)&Bs[cur][kk][tx * 4];
      *(float4*)&bb[4] = *(const float4*)&Bs[cur][kk][128 + tx * 4];
#pragma unroll
      for (int i = 0; i < 8; i++)
#pragma unroll
        for (int j = 0; j < 8; j++) acc[i][j] = fmaf(a[i], bb[j], acc[i][j]);
    }
    if (t < 15) {
      const int nxt = cur ^ 1;
      // safe: buf `nxt` was last read in iteration t-1; the sync at the end
      // of t-1 ordered all those reads before these writes.
      As[nxt][ak + 0][am] = ra.x;
      As[nxt][ak + 1][am] = ra.y;
      As[nxt][ak + 2][am] = ra.z;
      As[nxt][ak + 3][am] = ra.w;
      *(float4*)&Bs[nxt][bk][bn]       = rb0;
      *(float4*)&Bs[nxt][bk][bn + 64]  = rb1;
      *(float4*)&Bs[nxt][bk][bn + 128] = rb2;
      *(float4*)&Bs[nxt][bk][bn + 192] = rb3;
      __syncthreads();
      cur = nxt;
    }
  }

  float* outB = qkv + (size_t)b * NQKV * NHW;
#pragma unroll
  for (int i = 0; i < 8; i++) {
    const int m = m0 + ((i < 4) ? (ty * 4 + i) : (32 + ty * 4 + (i - 4)));
    float4 v0 = {acc[i][0], acc[i][1], acc[i][2], acc[i][3]};
    float4 v1 = {acc[i][4], acc[i][5], acc[i][6], acc[i][7]};
    float* r = outB + (size_t)m * NHW + n0;
    *(float4*)(r + tx * 4)       = v0;
    *(float4*)(r + 128 + tx * 4) = v1;
  }
}

// ---------------------------------------------------------------------------
// K2q: kv partial sums for attention groups 0..7 (sourced from qkv).
// kv[b][g][d][e] += sum_n relu(k)[d] * {v[e], 1}
// ---------------------------------------------------------------------------
__global__ __launch_bounds__(256, 4) void k2_qkv_kv(
    const float* __restrict__ qkv, float* __restrict__ kvb)
{
  __shared__ float red[4 * 72];
  const int tid = threadIdx.x;
  const int gg  = blockIdx.y;               // 0..7
  const int P0  = blockIdx.x * 2048;
  const int b   = P0 >> 14;
  const int n0  = P0 & (NHW - 1);

  const float* base = qkv + ((size_t)b * NQKV + gg * 24) * NHW + n0 + tid;

  float acc[72];
#pragma unroll
  for (int i = 0; i < 72; i++) acc[i] = 0.f;

  for (int it = 0; it < 8; it++) {
    const int off = it * 256;
    float kk[8], vv[8];
#pragma unroll
    for (int j = 0; j < 8; j++) kk[j] = fmaxf(base[(size_t)(8 + j) * NHW + off], 0.f);
#pragma unroll
    for (int j = 0; j < 8; j++) vv[j] = base[(size_t)(16 + j) * NHW + off];
#pragma unroll
    for (int d = 0; d < 8; d++) {
#pragma unroll
      for (int e = 0; e < 8; e++) acc[d * 9 + e] = fmaf(kk[d], vv[e], acc[d * 9 + e]);
      acc[d * 9 + 8] += kk[d];
    }
  }

  const int wave = tid >> 6, lane = tid & 63;
#pragma unroll
  for (int i = 0; i < 72; i++) {
    float v = acc[i];
    v += __shfl_down(v, 32);
    v += __shfl_down(v, 16);
    v += __shfl_down(v, 8);
    v += __shfl_down(v, 4);
    v += __shfl_down(v, 2);
    v += __shfl_down(v, 1);
    if (lane == 0) red[wave * 72 + i] = v;
  }
  __syncthreads();
  if (tid < 72) {
    float s = red[tid] + red[72 + tid] + red[144 + tid] + red[216 + tid];
    atomicAdd(&kvb[((size_t)b * 16 + gg) * 72 + tid], s);
  }
}

// ---------------------------------------------------------------------------
// K2d: for attention groups 8..15 (sourced from depthwise conv d):
//  - stage qkv halo (24 ch) in LDS, apply W_p in place -> p
//  - depthwise 3x3 -> d; write relu'd q-channels to dq; accumulate kv partials
// tile = 32 wide x 16 tall, halo 34x18
// ---------------------------------------------------------------------------
#define HALO_W 34
#define HALO_H 18
#define NPOS   (HALO_W * HALO_H)   // 612

__global__ __launch_bounds__(256, 2) void k2_dw(
    const float* __restrict__ qkv, const float* __restrict__ Wp,
    const float* __restrict__ Wd, float* __restrict__ dq,
    float* __restrict__ kvb)
{
  __shared__ float pbuf[24 * NPOS];
  __shared__ float red[4 * 72];

  const int tid  = threadIdx.x;
  const int gg8  = blockIdx.y;            // 0..7  (attention group = 8+gg8)
  const int bt   = blockIdx.x;            // b*32 + tile
  const int b    = bt >> 5;
  const int tile = bt & 31;
  const int ty0  = (tile >> 2) * 16;      // 8 tiles in y
  const int tx0  = (tile & 3) * 32;       // 4 tiles in x

  const float* src = qkv + ((size_t)b * NQKV + gg8 * 24) * NHW;

  // phase 1: load qkv halo into LDS (zero-padded)
  for (int idx = tid; idx < 24 * NPOS; idx += 256) {
    const int c = idx / NPOS, pos = idx % NPOS;
    const int hy = pos / HALO_W, hx = pos % HALO_W;
    const int y = ty0 + hy - 1, xx = tx0 + hx - 1;
    float v = 0.f;
    if (y >= 0 && y < NH && xx >= 0 && xx < NW) v = src[(size_t)c * NHW + y * NW + xx];
    pbuf[idx] = v;
  }
  __syncthreads();

  // phase 1b: apply W_p in place (each task owns its 8 LDS slots)
  for (int t = tid; t < 3 * NPOS; t += 256) {
    const int gloc = t / NPOS, pos = t % NPOS;
    float qv[8];
#pragma unroll
    for (int i = 0; i < 8; i++) qv[i] = pbuf[(gloc * 8 + i) * NPOS + pos];
    const float* wp = Wp + (size_t)(gg8 * 3 + gloc) * 64;
#pragma unroll
    for (int o = 0; o < 8; o++) {
      float s = 0.f;
#pragma unroll
      for (int i = 0; i < 8; i++) s = fmaf(wp[o * 8 + i], qv[i], s);
      pbuf[(gloc * 8 + o) * NPOS + pos] = s;
    }
  }
  __syncthreads();

  // phase 2: depthwise 3x3 + outputs
  float acc[72];
#pragma unroll
  for (int i = 0; i < 72; i++) acc[i] = 0.f;

  const float* wdb = Wd + (size_t)gg8 * 24 * 9;

  for (int pp = tid; pp < 512; pp += 256) {
    const int ty = pp >> 5, tx = pp & 31;
    const int n  = (ty0 + ty) * NW + (tx0 + tx);
    float kk[8], vv[8];
#pragma unroll
    for (int cc = 0; cc < 24; cc++) {
      const float* pb = pbuf + cc * NPOS + ty * HALO_W + tx;
      const float* w  = wdb + cc * 9;
      float s = 0.f;
      s = fmaf(w[0], pb[0], s);
      s = fmaf(w[1], pb[1], s);
      s = fmaf(w[2], pb[2], s);
      s = fmaf(w[3], pb[HALO_W + 0], s);
      s = fmaf(w[4], pb[HALO_W + 1], s);
      s = fmaf(w[5], pb[HALO_W + 2], s);
      s = fmaf(w[6], pb[2 * HALO_W + 0], s);
      s = fmaf(w[7], pb[2 * HALO_W + 1], s);
      s = fmaf(w[8], pb[2 * HALO_W + 2], s);
      if (cc < 8) {
        dq[((size_t)b * 64 + gg8 * 8 + cc) * NHW + n] = fmaxf(s, 0.f);
      } else if (cc < 16) {
        kk[cc - 8] = fmaxf(s, 0.f);
      } else {
        vv[cc - 16] = s;
      }
    }
#pragma unroll
    for (int d = 0; d < 8; d++) {
#pragma unroll
      for (int e = 0; e < 8; e++) acc[d * 9 + e] = fmaf(kk[d], vv[e], acc[d * 9 + e]);
      acc[d * 9 + 8] += kk[d];
    }
  }

  const int wave = tid >> 6, lane = tid & 63;
#pragma unroll
  for (int i = 0; i < 72; i++) {
    float v = acc[i];
    v += __shfl_down(v, 32);
    v += __shfl_down(v, 16);
    v += __shfl_down(v, 8);
    v += __shfl_down(v, 4);
    v += __shfl_down(v, 2);
    v += __shfl_down(v, 1);
    if (lane == 0) red[wave * 72 + i] = v;
  }
  __syncthreads();
  if (tid < 72) {
    float s = red[tid] + red[72 + tid] + red[144 + tid] + red[216 + tid];
    atomicAdd(&kvb[((size_t)b * 16 + (8 + gg8)) * 72 + tid], s);
  }
}

// ---------------------------------------------------------------------------
// K3: per pixel: q (16 groups x 8) -> o = (q . kv)[:8] / (q . kv)[8]
//     then y = Wffn @ o, BN affine.  M-tile 64 (grid.y=4), 4 waves/EU.
// ---------------------------------------------------------------------------
__global__ __launch_bounds__(256, 4) void k3_attn_ffn(
    const float* __restrict__ qkv, const float* __restrict__ dq,
    const float* __restrict__ kvb, const float* __restrict__ Wf,
    const float* __restrict__ gamma, const float* __restrict__ beta,
    const float* __restrict__ mean, const float* __restrict__ var,
    float* __restrict__ out)
{
  const int tid = threadIdx.x;
  const int P0  = blockIdx.x * 256;
  const int b   = P0 >> 14;
  const int n0  = P0 & (NHW - 1);
  const int m0  = blockIdx.y * 64;
  const int n   = n0 + tid;

  float acc[64];
#pragma unroll
  for (int m = 0; m < 64; m++) acc[m] = 0.f;

  const float* kvB = kvb + (size_t)b * 16 * 72;

  // prefetch q for group 0
  float q[8], qn[8];
  {
    const float* qp = qkv + ((size_t)b * NQKV + 0) * NHW + n;
#pragma unroll
    for (int j = 0; j < 8; j++) q[j] = qp[(size_t)j * NHW];
  }

  for (int g = 0; g < 16; g++) {
    // prefetch next group's q (raw)
    if (g < 15) {
      const int gn = g + 1;
      const float* qp = (gn < 8)
          ? qkv + ((size_t)b * NQKV + gn * 24) * NHW + n
          : dq + ((size_t)b * 64 + (gn - 8) * 8) * NHW + n;
#pragma unroll
      for (int j = 0; j < 8; j++) qn[j] = qp[(size_t)j * NHW];
    }

    float qv[8];
#pragma unroll
    for (int j = 0; j < 8; j++) qv[j] = (g < 8) ? fmaxf(q[j], 0.f) : q[j];

    const float* kvg = kvB + g * 72;
    float num[9];
#pragma unroll
    for (int e = 0; e < 9; e++) {
      float s = 0.f;
#pragma unroll
      for (int d = 0; d < 8; d++) s = fmaf(qv[d], kvg[d * 9 + e], s);
      num[e] = s;
    }
    const float r = __builtin_amdgcn_rcpf(num[8] + 1e-15f);
    float o8[8];
#pragma unroll
    for (int e = 0; e < 8; e++) o8[e] = num[e] * r;

    const float* wg = Wf + (size_t)m0 * 128 + g * 8;
#pragma unroll
    for (int m = 0; m < 64; m++) {
#pragma unroll
      for (int e = 0; e < 8; e++) acc[m] = fmaf(o8[e], wg[m * 128 + e], acc[m]);
    }

#pragma unroll
    for (int j = 0; j < 8; j++) q[j] = qn[j];
  }

  float* op = out + ((size_t)b * NCOUT + m0) * NHW + n;
#pragma unroll
  for (int m = 0; m < 64; m++) {
    const int oc = m0 + m;
    const float sc = gamma[oc] * __builtin_amdgcn_rsqf(var[oc] + 1e-5f);
    const float bi = fmaf(-mean[oc], sc, beta[oc]);
    op[(size_t)m * NHW] = fmaf(acc[m], sc, bi);
  }
}

// ---------------------------------------------------------------------------
extern "C" void kernel_launch(void* const* d_in, const int* in_sizes, int n_in,
                              void* d_out, int out_size, void* d_ws, size_t ws_size,
                              hipStream_t stream) {
  const float* x     = (const float*)d_in[0];
  const float* Wq    = (const float*)d_in[1];
  const float* Wp    = (const float*)d_in[2];
  const float* Wd    = (const float*)d_in[3];
  const float* Wf    = (const float*)d_in[4];
  const float* gamma = (const float*)d_in[5];
  const float* beta  = (const float*)d_in[6];
  const float* mean  = (const float*)d_in[7];
  const float* var   = (const float*)d_in[8];
  float* out = (float*)d_out;

  char* ws = (char*)d_ws;
  float* qkv = (float*)ws;                                   // 8*192*16384*4 = 96 MiB
  float* dq  = (float*)(ws + (size_t)100663296);             // 8*64*16384*4  = 32 MiB
  float* kvb = (float*)(ws + (size_t)134217728);             // 8*16*72*4     = 36 KiB

  hipMemsetAsync(kvb, 0, (size_t)NB * 16 * 72 * sizeof(float), stream);

  k1_qkv<<<dim3(512, 3), 256, 0, stream>>>(x, Wq, qkv);
  k2_qkv_kv<<<dim3(64, 8), 256, 0, stream>>>(qkv, kvb);
  k2_dw<<<dim3(256, 8), 256, 0, stream>>>(qkv, Wp, Wd, dq, kvb);
  k3_attn_ffn<<<dim3(512, 4), 256, 0, stream>>>(qkv, dq, kvb, Wf, gamma, beta,
                                                mean, var, out);
}

// Round 2
// 866.081 us; speedup vs baseline: 3.4270x; 3.4270x over previous
//
#include <hip/hip_runtime.h>

#define NB    8
#define NCIN  256
#define NH    128
#define NW    128
#define NHW   16384      // NH*NW
#define NQKV  192        // 3*T
#define NCOUT 256

// ---------------------------------------------------------------------------
// K1: qkv[b][m][n] = sum_k Wq[m][k] * x[b][k][n]   (1x1 conv as panel GEMM)
// Double-buffered LDS-tiled fp32 GEMM: BM=64, BN=256, BK=16, 256 threads,
// 8m x 8n register tile per thread.
// Round-1 lesson: __launch_bounds__(256,3) capped VGPRs at 84 -> acc[64]
// spilled to scratch -> 5.5 GB of scratch writes, VALUBusy 4%.  LDS (41 KB)
// already limits occupancy to 3 blocks/CU, so the hint bought nothing.
// No occupancy hint now; fragments unpacked via float4 temporaries with
// static indices only (keep everything SROA-promotable).
// ---------------------------------------------------------------------------
#define K1_BK  16
#define K1_LDA 68       // 64 + 4 pad
#define K1_LDB 260      // 256 + 4 pad

__global__ __launch_bounds__(256) void k1_qkv(
    const float* __restrict__ x, const float* __restrict__ Wq,
    float* __restrict__ qkv)
{
  __shared__ float As[2][K1_BK][K1_LDA];
  __shared__ float Bs[2][K1_BK][K1_LDB];

  const int tid = threadIdx.x;
  const int b   = blockIdx.x >> 6;          // 64 n-tiles per batch
  const int n0  = (blockIdx.x & 63) << 8;   // *256
  const int m0  = blockIdx.y << 6;          // *64

  // staging assignment
  const int am = tid >> 2;                  // 0..63  m within tile
  const int ak = (tid & 3) << 2;            // 0,4,8,12 k within tile
  const int bk = tid >> 4;                  // 0..15 k within tile
  const int bn = (tid & 15) << 2;           // 0..60 n base (stride 64)

  const float* aP = Wq + ((size_t)(m0 + am) << 8) + ak;
  const float* bP = x + (size_t)b * NCIN * NHW + (size_t)bk * NHW + n0 + bn;

  // compute-thread mapping: 32 n-groups x 8 m-groups
  const int tx = tid & 31;
  const int ty = tid >> 5;

  float4 ra, rb0, rb1, rb2, rb3;
  ra  = *(const float4*)aP;
  rb0 = *(const float4*)(bP);
  rb1 = *(const float4*)(bP + 64);
  rb2 = *(const float4*)(bP + 128);
  rb3 = *(const float4*)(bP + 192);

  As[0][ak + 0][am] = ra.x;
  As[0][ak + 1][am] = ra.y;
  As[0][ak + 2][am] = ra.z;
  As[0][ak + 3][am] = ra.w;
  *(float4*)&Bs[0][bk][bn]       = rb0;
  *(float4*)&Bs[0][bk][bn + 64]  = rb1;
  *(float4*)&Bs[0][bk][bn + 128] = rb2;
  *(float4*)&Bs[0][bk][bn + 192] = rb3;
  __syncthreads();

  float acc[8][8];
#pragma unroll
  for (int i = 0; i < 8; i++)
#pragma unroll
    for (int j = 0; j < 8; j++) acc[i][j] = 0.f;

  int cur = 0;
  for (int t = 0; t < 16; ++t) {
    if (t < 15) {
      const size_t k0 = (size_t)(t + 1) * K1_BK;
      ra = *(const float4*)(aP + k0);
      const float* bq = bP + k0 * NHW;
      rb0 = *(const float4*)(bq);
      rb1 = *(const float4*)(bq + 64);
      rb2 = *(const float4*)(bq + 128);
      rb3 = *(const float4*)(bq + 192);
    }
#pragma unroll
    for (int kk = 0; kk < K1_BK; ++kk) {
      const float4 a0 = *(const float4*)&As[cur][kk][ty * 4];
      const float4 a1 = *(const float4*)&As[cur][kk][32 + ty * 4];
      const float4 b0 = *(const float4*)&Bs[cur][kk][tx * 4];
      const float4 b1 = *(const float4*)&Bs[cur][kk][128 + tx * 4];
      const float a[8]  = {a0.x, a0.y, a0.z, a0.w, a1.x, a1.y, a1.z, a1.w};
      const float bb[8] = {b0.x, b0.y, b0.z, b0.w, b1.x, b1.y, b1.z, b1.w};
#pragma unroll
      for (int i = 0; i < 8; i++)
#pragma unroll
        for (int j = 0; j < 8; j++) acc[i][j] = fmaf(a[i], bb[j], acc[i][j]);
    }
    if (t < 15) {
      const int nxt = cur ^ 1;
      As[nxt][ak + 0][am] = ra.x;
      As[nxt][ak + 1][am] = ra.y;
      As[nxt][ak + 2][am] = ra.z;
      As[nxt][ak + 3][am] = ra.w;
      *(float4*)&Bs[nxt][bk][bn]       = rb0;
      *(float4*)&Bs[nxt][bk][bn + 64]  = rb1;
      *(float4*)&Bs[nxt][bk][bn + 128] = rb2;
      *(float4*)&Bs[nxt][bk][bn + 192] = rb3;
      __syncthreads();
      cur = nxt;
    }
  }

  float* outB = qkv + (size_t)b * NQKV * NHW;
#pragma unroll
  for (int i = 0; i < 8; i++) {
    const int m = m0 + ((i < 4) ? (ty * 4 + i) : (32 + ty * 4 + (i - 4)));
    float4 v0 = {acc[i][0], acc[i][1], acc[i][2], acc[i][3]};
    float4 v1 = {acc[i][4], acc[i][5], acc[i][6], acc[i][7]};
    float* r = outB + (size_t)m * NHW + n0;
    *(float4*)(r + tx * 4)       = v0;
    *(float4*)(r + 128 + tx * 4) = v1;
  }
}

// ---------------------------------------------------------------------------
// K2q: kv partial sums for attention groups 0..7 (sourced from qkv).
// kv[b][g][d][e] += sum_n relu(k)[d] * {v[e], 1}
// ---------------------------------------------------------------------------
__global__ __launch_bounds__(256, 4) void k2_qkv_kv(
    const float* __restrict__ qkv, float* __restrict__ kvb)
{
  __shared__ float red[4 * 72];
  const int tid = threadIdx.x;
  const int gg  = blockIdx.y;               // 0..7
  const int P0  = blockIdx.x * 2048;
  const int b   = P0 >> 14;
  const int n0  = P0 & (NHW - 1);

  const float* base = qkv + ((size_t)b * NQKV + gg * 24) * NHW + n0 + tid;

  float acc[72];
#pragma unroll
  for (int i = 0; i < 72; i++) acc[i] = 0.f;

  for (int it = 0; it < 8; it++) {
    const int off = it * 256;
    float kk[8], vv[8];
#pragma unroll
    for (int j = 0; j < 8; j++) kk[j] = fmaxf(base[(size_t)(8 + j) * NHW + off], 0.f);
#pragma unroll
    for (int j = 0; j < 8; j++) vv[j] = base[(size_t)(16 + j) * NHW + off];
#pragma unroll
    for (int d = 0; d < 8; d++) {
#pragma unroll
      for (int e = 0; e < 8; e++) acc[d * 9 + e] = fmaf(kk[d], vv[e], acc[d * 9 + e]);
      acc[d * 9 + 8] += kk[d];
    }
  }

  const int wave = tid >> 6, lane = tid & 63;
#pragma unroll
  for (int i = 0; i < 72; i++) {
    float v = acc[i];
    v += __shfl_down(v, 32);
    v += __shfl_down(v, 16);
    v += __shfl_down(v, 8);
    v += __shfl_down(v, 4);
    v += __shfl_down(v, 2);
    v += __shfl_down(v, 1);
    if (lane == 0) red[wave * 72 + i] = v;
  }
  __syncthreads();
  if (tid < 72) {
    float s = red[tid] + red[72 + tid] + red[144 + tid] + red[216 + tid];
    atomicAdd(&kvb[((size_t)b * 16 + gg) * 72 + tid], s);
  }
}

// ---------------------------------------------------------------------------
// K2d: for attention groups 8..15 (sourced from depthwise conv d):
//  - stage qkv halo (24 ch) in LDS, apply W_p in place -> p
//  - depthwise 3x3 -> d; write relu'd q-channels to dq; accumulate kv partials
// tile = 32 wide x 16 tall, halo 34x18
// ---------------------------------------------------------------------------
#define HALO_W 34
#define HALO_H 18
#define NPOS   (HALO_W * HALO_H)   // 612

__global__ __launch_bounds__(256, 2) void k2_dw(
    const float* __restrict__ qkv, const float* __restrict__ Wp,
    const float* __restrict__ Wd, float* __restrict__ dq,
    float* __restrict__ kvb)
{
  __shared__ float pbuf[24 * NPOS];
  __shared__ float red[4 * 72];

  const int tid  = threadIdx.x;
  const int gg8  = blockIdx.y;            // 0..7  (attention group = 8+gg8)
  const int bt   = blockIdx.x;            // b*32 + tile
  const int b    = bt >> 5;
  const int tile = bt & 31;
  const int ty0  = (tile >> 2) * 16;      // 8 tiles in y
  const int tx0  = (tile & 3) * 32;       // 4 tiles in x

  const float* src = qkv + ((size_t)b * NQKV + gg8 * 24) * NHW;

  // phase 1: load qkv halo into LDS (zero-padded)
  for (int idx = tid; idx < 24 * NPOS; idx += 256) {
    const int c = idx / NPOS, pos = idx % NPOS;
    const int hy = pos / HALO_W, hx = pos % HALO_W;
    const int y = ty0 + hy - 1, xx = tx0 + hx - 1;
    float v = 0.f;
    if (y >= 0 && y < NH && xx >= 0 && xx < NW) v = src[(size_t)c * NHW + y * NW + xx];
    pbuf[idx] = v;
  }
  __syncthreads();

  // phase 1b: apply W_p in place (each task owns its 8 LDS slots)
  for (int t = tid; t < 3 * NPOS; t += 256) {
    const int gloc = t / NPOS, pos = t % NPOS;
    float qv[8];
#pragma unroll
    for (int i = 0; i < 8; i++) qv[i] = pbuf[(gloc * 8 + i) * NPOS + pos];
    const float* wp = Wp + (size_t)(gg8 * 3 + gloc) * 64;
#pragma unroll
    for (int o = 0; o < 8; o++) {
      float s = 0.f;
#pragma unroll
      for (int i = 0; i < 8; i++) s = fmaf(wp[o * 8 + i], qv[i], s);
      pbuf[(gloc * 8 + o) * NPOS + pos] = s;
    }
  }
  __syncthreads();

  // phase 2: depthwise 3x3 + outputs
  float acc[72];
#pragma unroll
  for (int i = 0; i < 72; i++) acc[i] = 0.f;

  const float* wdb = Wd + (size_t)gg8 * 24 * 9;

  for (int pp = tid; pp < 512; pp += 256) {
    const int ty = pp >> 5, tx = pp & 31;
    const int n  = (ty0 + ty) * NW + (tx0 + tx);
    float kk[8], vv[8];
#pragma unroll
    for (int cc = 0; cc < 24; cc++) {
      const float* pb = pbuf + cc * NPOS + ty * HALO_W + tx;
      const float* w  = wdb + cc * 9;
      float s = 0.f;
      s = fmaf(w[0], pb[0], s);
      s = fmaf(w[1], pb[1], s);
      s = fmaf(w[2], pb[2], s);
      s = fmaf(w[3], pb[HALO_W + 0], s);
      s = fmaf(w[4], pb[HALO_W + 1], s);
      s = fmaf(w[5], pb[HALO_W + 2], s);
      s = fmaf(w[6], pb[2 * HALO_W + 0], s);
      s = fmaf(w[7], pb[2 * HALO_W + 1], s);
      s = fmaf(w[8], pb[2 * HALO_W + 2], s);
      if (cc < 8) {
        dq[((size_t)b * 64 + gg8 * 8 + cc) * NHW + n] = fmaxf(s, 0.f);
      } else if (cc < 16) {
        kk[cc - 8] = fmaxf(s, 0.f);
      } else {
        vv[cc - 16] = s;
      }
    }
#pragma unroll
    for (int d = 0; d < 8; d++) {
#pragma unroll
      for (int e = 0; e < 8; e++) acc[d * 9 + e] = fmaf(kk[d], vv[e], acc[d * 9 + e]);
      acc[d * 9 + 8] += kk[d];
    }
  }

  const int wave = tid >> 6, lane = tid & 63;
#pragma unroll
  for (int i = 0; i < 72; i++) {
    float v = acc[i];
    v += __shfl_down(v, 32);
    v += __shfl_down(v, 16);
    v += __shfl_down(v, 8);
    v += __shfl_down(v, 4);
    v += __shfl_down(v, 2);
    v += __shfl_down(v, 1);
    if (lane == 0) red[wave * 72 + i] = v;
  }
  __syncthreads();
  if (tid < 72) {
    float s = red[tid] + red[72 + tid] + red[144 + tid] + red[216 + tid];
    atomicAdd(&kvb[((size_t)b * 16 + (8 + gg8)) * 72 + tid], s);
  }
}

// ---------------------------------------------------------------------------
// K3: per pixel: q (16 groups x 8) -> o = (q . kv)[:8] / (q . kv)[8]
//     then y = Wffn @ o, BN affine.  M-tile 64 (grid.y=4), 4 waves/EU.
// ---------------------------------------------------------------------------
__global__ __launch_bounds__(256, 4) void k3_attn_ffn(
    const float* __restrict__ qkv, const float* __restrict__ dq,
    const float* __restrict__ kvb, const float* __restrict__ Wf,
    const float* __restrict__ gamma, const float* __restrict__ beta,
    const float* __restrict__ mean, const float* __restrict__ var,
    float* __restrict__ out)
{
  const int tid = threadIdx.x;
  const int P0  = blockIdx.x * 256;
  const int b   = P0 >> 14;
  const int n0  = P0 & (NHW - 1);
  const int m0  = blockIdx.y * 64;
  const int n   = n0 + tid;

  float acc[64];
#pragma unroll
  for (int m = 0; m < 64; m++) acc[m] = 0.f;

  const float* kvB = kvb + (size_t)b * 16 * 72;

  // prefetch q for group 0
  float q[8], qn[8];
  {
    const float* qp = qkv + ((size_t)b * NQKV + 0) * NHW + n;
#pragma unroll
    for (int j = 0; j < 8; j++) q[j] = qp[(size_t)j * NHW];
  }

  for (int g = 0; g < 16; g++) {
    // prefetch next group's q (raw)
    if (g < 15) {
      const int gn = g + 1;
      const float* qp = (gn < 8)
          ? qkv + ((size_t)b * NQKV + gn * 24) * NHW + n
          : dq + ((size_t)b * 64 + (gn - 8) * 8) * NHW + n;
#pragma unroll
      for (int j = 0; j < 8; j++) qn[j] = qp[(size_t)j * NHW];
    }

    float qv[8];
#pragma unroll
    for (int j = 0; j < 8; j++) qv[j] = (g < 8) ? fmaxf(q[j], 0.f) : q[j];

    const float* kvg = kvB + g * 72;
    float num[9];
#pragma unroll
    for (int e = 0; e < 9; e++) {
      float s = 0.f;
#pragma unroll
      for (int d = 0; d < 8; d++) s = fmaf(qv[d], kvg[d * 9 + e], s);
      num[e] = s;
    }
    const float r = __builtin_amdgcn_rcpf(num[8] + 1e-15f);
    float o8[8];
#pragma unroll
    for (int e = 0; e < 8; e++) o8[e] = num[e] * r;

    const float* wg = Wf + (size_t)m0 * 128 + g * 8;
#pragma unroll
    for (int m = 0; m < 64; m++) {
#pragma unroll
      for (int e = 0; e < 8; e++) acc[m] = fmaf(o8[e], wg[m * 128 + e], acc[m]);
    }

#pragma unroll
    for (int j = 0; j < 8; j++) q[j] = qn[j];
  }

  float* op = out + ((size_t)b * NCOUT + m0) * NHW + n;
#pragma unroll
  for (int m = 0; m < 64; m++) {
    const int oc = m0 + m;
    const float sc = gamma[oc] * __builtin_amdgcn_rsqf(var[oc] + 1e-5f);
    const float bi = fmaf(-mean[oc], sc, beta[oc]);
    op[(size_t)m * NHW] = fmaf(acc[m], sc, bi);
  }
}

// ---------------------------------------------------------------------------
extern "C" void kernel_launch(void* const* d_in, const int* in_sizes, int n_in,
                              void* d_out, int out_size, void* d_ws, size_t ws_size,
                              hipStream_t stream) {
  const float* x     = (const float*)d_in[0];
  const float* Wq    = (const float*)d_in[1];
  const float* Wp    = (const float*)d_in[2];
  const float* Wd    = (const float*)d_in[3];
  const float* Wf    = (const float*)d_in[4];
  const float* gamma = (const float*)d_in[5];
  const float* beta  = (const float*)d_in[6];
  const float* mean  = (const float*)d_in[7];
  const float* var   = (const float*)d_in[8];
  float* out = (float*)d_out;

  char* ws = (char*)d_ws;
  float* qkv = (float*)ws;                                   // 8*192*16384*4 = 96 MiB
  float* dq  = (float*)(ws + (size_t)100663296);             // 8*64*16384*4  = 32 MiB
  float* kvb = (float*)(ws + (size_t)134217728);             // 8*16*72*4     = 36 KiB

  hipMemsetAsync(kvb, 0, (size_t)NB * 16 * 72 * sizeof(float), stream);

  k1_qkv<<<dim3(512, 3), 256, 0, stream>>>(x, Wq, qkv);
  k2_qkv_kv<<<dim3(64, 8), 256, 0, stream>>>(qkv, kvb);
  k2_dw<<<dim3(256, 8), 256, 0, stream>>>(qkv, Wp, Wd, dq, kvb);
  k3_attn_ffn<<<dim3(512, 4), 256, 0, stream>>>(qkv, dq, kvb, Wf, gamma, beta,
                                                mean, var, out);
}

// Round 3
// 725.090 us; speedup vs baseline: 4.0933x; 1.1944x over previous
//
#include <hip/hip_runtime.h>

#define NB    8
#define NCIN  256
#define NH    128
#define NW    128
#define NHW   16384      // NH*NW
#define NQKV  192        // 3*T
#define NCOUT 256

// ---------------------------------------------------------------------------
// K1: qkv[b][m][n] = sum_k Wq[m][k] * x[b][k][n]   (1x1 conv as panel GEMM)
// Double-buffered LDS-tiled fp32 GEMM: BM=64, BN=256, BK=16, 256 threads,
// 8m x 8n register tile per thread.  NOTE: no __launch_bounds__ min-waves —
// round-1 showed a (256,3) hint caps VGPRs at 84 and spills acc to scratch
// (5.5 GB of scratch traffic, 2.2 ms).  LDS already caps occupancy.
// ---------------------------------------------------------------------------
#define K1_BK  16
#define K1_LDA 68       // 64 + 4 pad
#define K1_LDB 260      // 256 + 4 pad

__global__ __launch_bounds__(256) void k1_qkv(
    const float* __restrict__ x, const float* __restrict__ Wq,
    float* __restrict__ qkv)
{
  __shared__ float As[2][K1_BK][K1_LDA];
  __shared__ float Bs[2][K1_BK][K1_LDB];

  const int tid = threadIdx.x;
  const int b   = blockIdx.x >> 6;          // 64 n-tiles per batch
  const int n0  = (blockIdx.x & 63) << 8;   // *256
  const int m0  = blockIdx.y << 6;          // *64

  // staging assignment
  const int am = tid >> 2;                  // 0..63  m within tile
  const int ak = (tid & 3) << 2;            // 0,4,8,12 k within tile
  const int bk = tid >> 4;                  // 0..15 k within tile
  const int bn = (tid & 15) << 2;           // 0..60 n base (stride 64)

  const float* aP = Wq + ((size_t)(m0 + am) << 8) + ak;
  const float* bP = x + (size_t)b * NCIN * NHW + (size_t)bk * NHW + n0 + bn;

  // compute-thread mapping: 32 n-groups x 8 m-groups
  const int tx = tid & 31;
  const int ty = tid >> 5;

  float4 ra, rb0, rb1, rb2, rb3;
  ra  = *(const float4*)aP;
  rb0 = *(const float4*)(bP);
  rb1 = *(const float4*)(bP + 64);
  rb2 = *(const float4*)(bP + 128);
  rb3 = *(const float4*)(bP + 192);

  As[0][ak + 0][am] = ra.x;
  As[0][ak + 1][am] = ra.y;
  As[0][ak + 2][am] = ra.z;
  As[0][ak + 3][am] = ra.w;
  *(float4*)&Bs[0][bk][bn]       = rb0;
  *(float4*)&Bs[0][bk][bn + 64]  = rb1;
  *(float4*)&Bs[0][bk][bn + 128] = rb2;
  *(float4*)&Bs[0][bk][bn + 192] = rb3;
  __syncthreads();

  float acc[8][8];
#pragma unroll
  for (int i = 0; i < 8; i++)
#pragma unroll
    for (int j = 0; j < 8; j++) acc[i][j] = 0.f;

  int cur = 0;
  for (int t = 0; t < 16; ++t) {
    if (t < 15) {
      const size_t k0 = (size_t)(t + 1) * K1_BK;
      ra = *(const float4*)(aP + k0);
      const float* bq = bP + k0 * NHW;
      rb0 = *(const float4*)(bq);
      rb1 = *(const float4*)(bq + 64);
      rb2 = *(const float4*)(bq + 128);
      rb3 = *(const float4*)(bq + 192);
    }
#pragma unroll
    for (int kk = 0; kk < K1_BK; ++kk) {
      const float4 a0 = *(const float4*)&As[cur][kk][ty * 4];
      const float4 a1 = *(const float4*)&As[cur][kk][32 + ty * 4];
      const float4 b0 = *(const float4*)&Bs[cur][kk][tx * 4];
      const float4 b1 = *(const float4*)&Bs[cur][kk][128 + tx * 4];
      const float a[8]  = {a0.x, a0.y, a0.z, a0.w, a1.x, a1.y, a1.z, a1.w};
      const float bb[8] = {b0.x, b0.y, b0.z, b0.w, b1.x, b1.y, b1.z, b1.w};
#pragma unroll
      for (int i = 0; i < 8; i++)
#pragma unroll
        for (int j = 0; j < 8; j++) acc[i][j] = fmaf(a[i], bb[j], acc[i][j]);
    }
    if (t < 15) {
      const int nxt = cur ^ 1;
      As[nxt][ak + 0][am] = ra.x;
      As[nxt][ak + 1][am] = ra.y;
      As[nxt][ak + 2][am] = ra.z;
      As[nxt][ak + 3][am] = ra.w;
      *(float4*)&Bs[nxt][bk][bn]       = rb0;
      *(float4*)&Bs[nxt][bk][bn + 64]  = rb1;
      *(float4*)&Bs[nxt][bk][bn + 128] = rb2;
      *(float4*)&Bs[nxt][bk][bn + 192] = rb3;
      __syncthreads();
      cur = nxt;
    }
  }

  float* outB = qkv + (size_t)b * NQKV * NHW;
#pragma unroll
  for (int i = 0; i < 8; i++) {
    const int m = m0 + ((i < 4) ? (ty * 4 + i) : (32 + ty * 4 + (i - 4)));
    float4 v0 = {acc[i][0], acc[i][1], acc[i][2], acc[i][3]};
    float4 v1 = {acc[i][4], acc[i][5], acc[i][6], acc[i][7]};
    float* r = outB + (size_t)m * NHW + n0;
    *(float4*)(r + tx * 4)       = v0;
    *(float4*)(r + 128 + tx * 4) = v1;
  }
}

// ---------------------------------------------------------------------------
// K2q: kv partial sums for attention groups 0..7 (sourced from qkv).
// ---------------------------------------------------------------------------
__global__ __launch_bounds__(256, 4) void k2_qkv_kv(
    const float* __restrict__ qkv, float* __restrict__ kvb)
{
  __shared__ float red[4 * 72];
  const int tid = threadIdx.x;
  const int gg  = blockIdx.y;               // 0..7
  const int P0  = blockIdx.x * 2048;
  const int b   = P0 >> 14;
  const int n0  = P0 & (NHW - 1);

  const float* base = qkv + ((size_t)b * NQKV + gg * 24) * NHW + n0 + tid;

  float acc[72];
#pragma unroll
  for (int i = 0; i < 72; i++) acc[i] = 0.f;

  for (int it = 0; it < 8; it++) {
    const int off = it * 256;
    float kk[8], vv[8];
#pragma unroll
    for (int j = 0; j < 8; j++) kk[j] = fmaxf(base[(size_t)(8 + j) * NHW + off], 0.f);
#pragma unroll
    for (int j = 0; j < 8; j++) vv[j] = base[(size_t)(16 + j) * NHW + off];
#pragma unroll
    for (int d = 0; d < 8; d++) {
#pragma unroll
      for (int e = 0; e < 8; e++) acc[d * 9 + e] = fmaf(kk[d], vv[e], acc[d * 9 + e]);
      acc[d * 9 + 8] += kk[d];
    }
  }

  const int wave = tid >> 6, lane = tid & 63;
#pragma unroll
  for (int i = 0; i < 72; i++) {
    float v = acc[i];
    v += __shfl_down(v, 32);
    v += __shfl_down(v, 16);
    v += __shfl_down(v, 8);
    v += __shfl_down(v, 4);
    v += __shfl_down(v, 2);
    v += __shfl_down(v, 1);
    if (lane == 0) red[wave * 72 + i] = v;
  }
  __syncthreads();
  if (tid < 72) {
    float s = red[tid] + red[72 + tid] + red[144 + tid] + red[216 + tid];
    atomicAdd(&kvb[((size_t)b * 16 + gg) * 72 + tid], s);
  }
}

// ---------------------------------------------------------------------------
// K2d: groups 8..15 — stage qkv halo, W_p in LDS, depthwise 3x3, kv partials.
// ---------------------------------------------------------------------------
#define HALO_W 34
#define HALO_H 18
#define NPOS   (HALO_W * HALO_H)   // 612

__global__ __launch_bounds__(256, 2) void k2_dw(
    const float* __restrict__ qkv, const float* __restrict__ Wp,
    const float* __restrict__ Wd, float* __restrict__ dq,
    float* __restrict__ kvb)
{
  __shared__ float pbuf[24 * NPOS];
  __shared__ float red[4 * 72];

  const int tid  = threadIdx.x;
  const int gg8  = blockIdx.y;            // 0..7  (attention group = 8+gg8)
  const int bt   = blockIdx.x;            // b*32 + tile
  const int b    = bt >> 5;
  const int tile = bt & 31;
  const int ty0  = (tile >> 2) * 16;      // 8 tiles in y
  const int tx0  = (tile & 3) * 32;       // 4 tiles in x

  const float* src = qkv + ((size_t)b * NQKV + gg8 * 24) * NHW;

  for (int idx = tid; idx < 24 * NPOS; idx += 256) {
    const int c = idx / NPOS, pos = idx % NPOS;
    const int hy = pos / HALO_W, hx = pos % HALO_W;
    const int y = ty0 + hy - 1, xx = tx0 + hx - 1;
    float v = 0.f;
    if (y >= 0 && y < NH && xx >= 0 && xx < NW) v = src[(size_t)c * NHW + y * NW + xx];
    pbuf[idx] = v;
  }
  __syncthreads();

  for (int t = tid; t < 3 * NPOS; t += 256) {
    const int gloc = t / NPOS, pos = t % NPOS;
    float qv[8];
#pragma unroll
    for (int i = 0; i < 8; i++) qv[i] = pbuf[(gloc * 8 + i) * NPOS + pos];
    const float* wp = Wp + (size_t)(gg8 * 3 + gloc) * 64;
#pragma unroll
    for (int o = 0; o < 8; o++) {
      float s = 0.f;
#pragma unroll
      for (int i = 0; i < 8; i++) s = fmaf(wp[o * 8 + i], qv[i], s);
      pbuf[(gloc * 8 + o) * NPOS + pos] = s;
    }
  }
  __syncthreads();

  float acc[72];
#pragma unroll
  for (int i = 0; i < 72; i++) acc[i] = 0.f;

  const float* wdb = Wd + (size_t)gg8 * 24 * 9;

  for (int pp = tid; pp < 512; pp += 256) {
    const int ty = pp >> 5, tx = pp & 31;
    const int n  = (ty0 + ty) * NW + (tx0 + tx);
    float kk[8], vv[8];
#pragma unroll
    for (int cc = 0; cc < 24; cc++) {
      const float* pb = pbuf + cc * NPOS + ty * HALO_W + tx;
      const float* w  = wdb + cc * 9;
      float s = 0.f;
      s = fmaf(w[0], pb[0], s);
      s = fmaf(w[1], pb[1], s);
      s = fmaf(w[2], pb[2], s);
      s = fmaf(w[3], pb[HALO_W + 0], s);
      s = fmaf(w[4], pb[HALO_W + 1], s);
      s = fmaf(w[5], pb[HALO_W + 2], s);
      s = fmaf(w[6], pb[2 * HALO_W + 0], s);
      s = fmaf(w[7], pb[2 * HALO_W + 1], s);
      s = fmaf(w[8], pb[2 * HALO_W + 2], s);
      if (cc < 8) {
        dq[((size_t)b * 64 + gg8 * 8 + cc) * NHW + n] = fmaxf(s, 0.f);
      } else if (cc < 16) {
        kk[cc - 8] = fmaxf(s, 0.f);
      } else {
        vv[cc - 16] = s;
      }
    }
#pragma unroll
    for (int d = 0; d < 8; d++) {
#pragma unroll
      for (int e = 0; e < 8; e++) acc[d * 9 + e] = fmaf(kk[d], vv[e], acc[d * 9 + e]);
      acc[d * 9 + 8] += kk[d];
    }
  }

  const int wave = tid >> 6, lane = tid & 63;
#pragma unroll
  for (int i = 0; i < 72; i++) {
    float v = acc[i];
    v += __shfl_down(v, 32);
    v += __shfl_down(v, 16);
    v += __shfl_down(v, 8);
    v += __shfl_down(v, 4);
    v += __shfl_down(v, 2);
    v += __shfl_down(v, 1);
    if (lane == 0) red[wave * 72 + i] = v;
  }
  __syncthreads();
  if (tid < 72) {
    float s = red[tid] + red[72 + tid] + red[144 + tid] + red[216 + tid];
    atomicAdd(&kvb[((size_t)b * 16 + (8 + gg8)) * 72 + tid], s);
  }
}

// ---------------------------------------------------------------------------
// K3: per pixel: q (16 groups x 8) -> o = (q . kv)[:8] / (q . kv)[8]
//     then y = Wffn @ o, BN affine.
// Rewritten round 3.  Old version: __launch_bounds__(256,4) forced acc[64]
// into AGPRs (VGPR_Count=52) with v_accvgpr shuttling per FMA, and streamed
// 32 KB/block of uniform Wf through the chunked s_load path -> VALUBusy 34%,
// 283 us.  Now:
//   - Wf m-panel (64x128 = 32 KB) staged once in LDS; weight reads are
//     wave-uniform ds_read_b128 broadcasts.
//   - attention output o8 computed ONCE per pixel (phase A, 1 px/thread),
//     shared via double-buffered oS[2][8][256] in LDS ([e][px] layout =
//     conflict-free b32), one __syncthreads per group.
//   - phase B: thread (ty,tx) owns 16 m x 4 px -> acc[16][4] = 64 VGPRs,
//     512 FMA per group against 40 LDS reads.  No occupancy hint.
// ---------------------------------------------------------------------------
__global__ __launch_bounds__(256) void k3_attn_ffn(
    const float* __restrict__ qkv, const float* __restrict__ dq,
    const float* __restrict__ kvb, const float* __restrict__ Wf,
    const float* __restrict__ gamma, const float* __restrict__ beta,
    const float* __restrict__ mean, const float* __restrict__ var,
    float* __restrict__ out)
{
  __shared__ float wS[64 * 128];        // 32 KB: Wf[m0..m0+63][0..127]
  __shared__ float oS[2][8][256];       // 16 KB: double-buffered o8 per pixel

  const int tid = threadIdx.x;
  const int b   = blockIdx.x >> 6;          // 64 blocks per batch
  const int n0  = (blockIdx.x & 63) << 8;   // 256 pixels per block
  const int m0  = blockIdx.y << 6;          // 64 out-channels per y-tile
  const int tx  = tid & 63;
  const int ty  = tid >> 6;                 // wave id: m-subgroup

  // stage Wf panel (8192 floats, 8x float4 per thread; i*1024+tid*4 keeps
  // the b128 writes spread across banks)
  {
    const float* wsrc = Wf + (size_t)m0 * 128;
#pragma unroll
    for (int i = 0; i < 8; ++i) {
      const int off = i * 1024 + tid * 4;
      *(float4*)&wS[off] = *(const float4*)&wsrc[off];
    }
  }

  float acc[16][4];
#pragma unroll
  for (int m = 0; m < 16; ++m)
#pragma unroll
    for (int p = 0; p < 4; ++p) acc[m][p] = 0.f;

  const float* kvB = kvb + (size_t)b * 16 * 72;

  for (int g = 0; g < 16; ++g) {
    // ---- phase A: this thread computes o8 for pixel (n0 + tid) ----
    const float* qp = (g < 8)
        ? qkv + ((size_t)b * NQKV + g * 24) * NHW + n0 + tid
        : dq  + ((size_t)b * 64 + (g - 8) * 8) * NHW + n0 + tid;
    float qv[8];
#pragma unroll
    for (int j = 0; j < 8; ++j) {
      const float v = qp[(size_t)j * NHW];
      qv[j] = (g < 8) ? fmaxf(v, 0.f) : v;
    }
    const float* kvg = kvB + g * 72;   // uniform -> scalar loads
    float num[9];
#pragma unroll
    for (int e = 0; e < 9; ++e) {
      float s = 0.f;
#pragma unroll
      for (int d = 0; d < 8; ++d) s = fmaf(qv[d], kvg[d * 9 + e], s);
      num[e] = s;
    }
    const float r = __builtin_amdgcn_rcpf(num[8] + 1e-15f);
    const int buf = g & 1;
#pragma unroll
    for (int e = 0; e < 8; ++e) oS[buf][e][tid] = num[e] * r;

    __syncthreads();   // oS[buf] ready (also orders next overwrite of buf^1)

    // ---- phase B: 16 m x 4 px FMAs from LDS ----
    float ov[4][8];
#pragma unroll
    for (int p = 0; p < 4; ++p)
#pragma unroll
      for (int e = 0; e < 8; ++e) ov[p][e] = oS[buf][e][tx + p * 64];

    const float* wrow = &wS[(ty * 16) * 128 + g * 8];
#pragma unroll
    for (int m = 0; m < 16; ++m) {
      const float4 w0 = *(const float4*)&wrow[m * 128];
      const float4 w1 = *(const float4*)&wrow[m * 128 + 4];
      const float w8[8] = {w0.x, w0.y, w0.z, w0.w, w1.x, w1.y, w1.z, w1.w};
#pragma unroll
      for (int p = 0; p < 4; ++p)
#pragma unroll
        for (int e = 0; e < 8; ++e)
          acc[m][p] = fmaf(ov[p][e], w8[e], acc[m][p]);
    }
  }

  // epilogue: BN affine + store (tx-coalesced)
#pragma unroll
  for (int m = 0; m < 16; ++m) {
    const int oc = m0 + ty * 16 + m;
    const float sc = gamma[oc] * __builtin_amdgcn_rsqf(var[oc] + 1e-5f);
    const float bi = fmaf(-mean[oc], sc, beta[oc]);
    float* op = out + ((size_t)b * NCOUT + oc) * NHW + n0 + tx;
#pragma unroll
    for (int p = 0; p < 4; ++p) op[p * 64] = fmaf(acc[m][p], sc, bi);
  }
}

// ---------------------------------------------------------------------------
extern "C" void kernel_launch(void* const* d_in, const int* in_sizes, int n_in,
                              void* d_out, int out_size, void* d_ws, size_t ws_size,
                              hipStream_t stream) {
  const float* x     = (const float*)d_in[0];
  const float* Wq    = (const float*)d_in[1];
  const float* Wp    = (const float*)d_in[2];
  const float* Wd    = (const float*)d_in[3];
  const float* Wf    = (const float*)d_in[4];
  const float* gamma = (const float*)d_in[5];
  const float* beta  = (const float*)d_in[6];
  const float* mean  = (const float*)d_in[7];
  const float* var   = (const float*)d_in[8];
  float* out = (float*)d_out;

  char* ws = (char*)d_ws;
  float* qkv = (float*)ws;                                   // 8*192*16384*4 = 96 MiB
  float* dq  = (float*)(ws + (size_t)100663296);             // 8*64*16384*4  = 32 MiB
  float* kvb = (float*)(ws + (size_t)134217728);             // 8*16*72*4     = 36 KiB

  hipMemsetAsync(kvb, 0, (size_t)NB * 16 * 72 * sizeof(float), stream);

  k1_qkv<<<dim3(512, 3), 256, 0, stream>>>(x, Wq, qkv);
  k2_qkv_kv<<<dim3(64, 8), 256, 0, stream>>>(qkv, kvb);
  k2_dw<<<dim3(256, 8), 256, 0, stream>>>(qkv, Wp, Wd, dq, kvb);
  k3_attn_ffn<<<dim3(512, 4), 256, 0, stream>>>(qkv, dq, kvb, Wf, gamma, beta,
                                                mean, var, out);
}